// Round 9
// baseline (74.824 us; speedup 1.0000x reference)
//
#include <hip/hip_runtime.h>

#define BB 4
#define NN 4096
#define TPB 1024             // 16 waves
#define IBL 64               // i's per block (IPT=2 per lane)
#define STREAMS 32           // 16 waves x 2 half-waves
#define JPS (NN / STREAMS)   // 128 j's per stream
#define GRP 4                // LDS prefetch depth

#if __has_builtin(__builtin_amdgcn_sqrtf)
  #define FAST_SQRT __builtin_amdgcn_sqrtf
#else
  #define FAST_SQRT sqrtf
#endif

__device__ __forceinline__ float clip1(float x) {
    return fminf(fmaxf(x, -1.0f), 1.0f);   // -> v_med3_f32
}

// ONE kernel, no workspace. Block = (b, 64-i chunk); lane owns 2 i's
// (li and li+32). Phase 0: stage batch b's 4096 float4(x,y,z,r) in LDS.
// Phase 1: 32 half-wave streams x 128 consecutive j's; per iteration ONE
// ds_read_b128 serves 128 pairs (64 lanes x 2 i's). Dot-trick miss path:
// sd = nj - 2*pi.pj, test sd < 4 - ni (exact skip: target <= 2, d2 >= 4).
// Taken path reconstructs d2 and exact dx,dy,dz (diagonal -> clip(0)=0).
// Phase 2: LDS-reuse reduction over streams (ascending j => deterministic),
// epilogue writes out directly. Grid 256 = 1 block/CU, 16 waves/CU.
__global__ __launch_bounds__(TPB, 4) void ncp_one(
    const float* __restrict__ coords,   // [BB,NN,3]
    const float* __restrict__ radii,    // [BB,NN]
    float* __restrict__ out)
{
    __shared__ __align__(16) char smem[65536];
    float4* pts = (float4*)smem;        // [NN] phases 0/1
    float*  red = (float*)smem;         // [STREAMS*IBL*3] phase 2 (24 KB)

    const int b = blockIdx.z;
    const int ibase = blockIdx.x * IBL;

    for (int p = threadIdx.x; p < NN; p += TPB) {
        const int g = b * NN + p;
        pts[p] = make_float4(coords[3 * g + 0], coords[3 * g + 1],
                             coords[3 * g + 2], radii[g]);
    }
    __syncthreads();

    const int l = threadIdx.x & 63;
    const int li = l & 31;
    const int half = l >> 5;
    const int w = threadIdx.x >> 6;
    const int stream = w * 2 + half;
    const int jbase = stream * JPS;

    // Two i's per lane.
    const float4 me0 = pts[ibase + li];
    const float4 me1 = pts[ibase + 32 + li];
    const float m2x0 = -2.0f * me0.x, m2y0 = -2.0f * me0.y, m2z0 = -2.0f * me0.z;
    const float m2x1 = -2.0f * me1.x, m2y1 = -2.0f * me1.y, m2z1 = -2.0f * me1.z;
    const float ri0 = me0.w, ri1 = me1.w;
    const float n20 = fmaf(me0.z, me0.z, fmaf(me0.y, me0.y, me0.x * me0.x));
    const float n21 = fmaf(me1.z, me1.z, fmaf(me1.y, me1.y, me1.x * me1.x));
    const float thr0 = 4.0f - n20;
    const float thr1 = 4.0f - n21;

    float ax0 = 0.0f, ay0 = 0.0f, az0 = 0.0f;
    float ax1 = 0.0f, ay1 = 0.0f, az1 = 0.0f;

    for (int k0 = 0; k0 < JPS; k0 += GRP) {
        float4 c[GRP];
        #pragma unroll
        for (int g = 0; g < GRP; ++g)
            c[g] = pts[jbase + k0 + g];     // half-wave-uniform: free 2-way
        #pragma unroll
        for (int g = 0; g < GRP; ++g) {
            const float nj = fmaf(c[g].z, c[g].z,
                             fmaf(c[g].y, c[g].y, c[g].x * c[g].x));
            const float sd0 = fmaf(m2z0, c[g].z,
                              fmaf(m2y0, c[g].y, fmaf(m2x0, c[g].x, nj)));
            const float sd1 = fmaf(m2z1, c[g].z,
                              fmaf(m2y1, c[g].y, fmaf(m2x1, c[g].x, nj)));
            if (__any(sd0 < thr0)) {
                const float dist = FAST_SQRT(fmaxf(sd0 + n20, 0.0f));
                const float tgt  = fmaxf(1.0f, ri0 + c[g].w);
                const float p    = fmaxf(tgt - dist, 0.0f);
                const float dx   = fmaf(-0.5f, m2x0, -c[g].x);
                const float dy   = fmaf(-0.5f, m2y0, -c[g].y);
                const float dz   = fmaf(-0.5f, m2z0, -c[g].z);
                ax0 = fmaf(p, clip1(dx), ax0);
                ay0 = fmaf(p, clip1(dy), ay0);
                az0 = fmaf(p, clip1(dz), az0);
            }
            if (__any(sd1 < thr1)) {
                const float dist = FAST_SQRT(fmaxf(sd1 + n21, 0.0f));
                const float tgt  = fmaxf(1.0f, ri1 + c[g].w);
                const float p    = fmaxf(tgt - dist, 0.0f);
                const float dx   = fmaf(-0.5f, m2x1, -c[g].x);
                const float dy   = fmaf(-0.5f, m2y1, -c[g].y);
                const float dz   = fmaf(-0.5f, m2z1, -c[g].z);
                ax1 = fmaf(p, clip1(dx), ax1);
                ay1 = fmaf(p, clip1(dy), ay1);
                az1 = fmaf(p, clip1(dz), az1);
            }
        }
    }

    __syncthreads();                    // all pts reads done before reuse
    {
        const int r0 = (stream * IBL + li) * 3;
        const int r1 = (stream * IBL + 32 + li) * 3;
        red[r0 + 0] = ax0; red[r0 + 1] = ay0; red[r0 + 2] = az0;
        red[r1 + 0] = ax1; red[r1 + 1] = ay1; red[r1 + 2] = az1;
    }
    __syncthreads();

    if (threadIdx.x < IBL * 3) {
        const int ii = threadIdx.x / 3;
        const int comp = threadIdx.x % 3;
        float acc = 0.0f;
        #pragma unroll
        for (int s = 0; s < STREAMS; ++s)   // ascending s == ascending j
            acc += red[(s * IBL + ii) * 3 + comp];
        const int o = (b * NN + ibase) * 3 + threadIdx.x;
        out[o] = fmaf(0.1f / (float)NN, acc, coords[o]);
    }
}

extern "C" void kernel_launch(void* const* d_in, const int* in_sizes, int n_in,
                              void* d_out, int out_size, void* d_ws, size_t ws_size,
                              hipStream_t stream) {
    const float* coords = (const float*)d_in[0];
    const float* radii  = (const float*)d_in[1];
    float* out = (float*)d_out;
    (void)d_ws; (void)ws_size;

    ncp_one<<<dim3(NN / IBL, 1, BB), TPB, 0, stream>>>(coords, radii, out);
}

// Round 10
// 73.419 us; speedup vs baseline: 1.0191x; 1.0191x over previous
//
#include <hip/hip_runtime.h>

#define BB 4
#define NN 4096
#define TPB 1024             // 16 waves
#define IBL 32               // i's per block (16 lane-slots x IPT=2)
#define STREAMS 64           // 16 waves x 4 quarter-waves
#define JPS (NN / STREAMS)   // 64 j's per stream
#define GRP 4                // LDS prefetch depth

#if __has_builtin(__builtin_amdgcn_sqrtf)
  #define FAST_SQRT __builtin_amdgcn_sqrtf
#else
  #define FAST_SQRT sqrtf
#endif

__device__ __forceinline__ float clip1(float x) {
    return fminf(fmaxf(x, -1.0f), 1.0f);   // -> v_med3_f32
}

// ONE dispatch, no workspace. Block = (b, 32-i chunk); lane owns 2 i's
// (li = l&15 and li+16). 64 quarter-wave streams x 64 consecutive j's each;
// one ds_read_b128 (4-way aliased, 1.58x - m136) serves 128 pairs.
// Grid 512 = 2 blocks/CU (128 KB LDS), 32 waves/CU = 8/SIMD: R7 occupancy
// with half R7's wave-iterations (the cell R8 missed).
// Early-out exact: radii in [0,1] -> target <= 2; d2 >= 4 -> penalty == 0.
// Diagonal: dx computed exactly -> clip(0) = 0 (matches reference).
// Phase 2: LDS-reuse reduction over streams in ascending-j order.
__global__ __launch_bounds__(TPB, 8) void ncp_one(
    const float* __restrict__ coords,   // [BB,NN,3]
    const float* __restrict__ radii,    // [BB,NN]
    float* __restrict__ out)
{
    __shared__ __align__(16) char smem[65536];
    float4* pts = (float4*)smem;        // [NN] phases 0/1
    float*  red = (float*)smem;         // [STREAMS][IBL][3] phase 2 (24 KB)

    const int b = blockIdx.z;
    const int ibase = blockIdx.x * IBL;

    for (int p = threadIdx.x; p < NN; p += TPB) {
        const int g = b * NN + p;
        pts[p] = make_float4(coords[3 * g + 0], coords[3 * g + 1],
                             coords[3 * g + 2], radii[g]);
    }
    __syncthreads();

    const int l = threadIdx.x & 63;
    const int li = l & 15;
    const int q  = l >> 4;              // quarter-wave 0..3
    const int w  = threadIdx.x >> 6;    // wave 0..15
    const int stream = w * 4 + q;       // 0..63
    const int jbase = stream * JPS;

    const float4 me0 = pts[ibase + li];
    const float4 me1 = pts[ibase + 16 + li];
    const float m2x0 = -2.0f * me0.x, m2y0 = -2.0f * me0.y, m2z0 = -2.0f * me0.z;
    const float m2x1 = -2.0f * me1.x, m2y1 = -2.0f * me1.y, m2z1 = -2.0f * me1.z;
    const float ri0 = me0.w, ri1 = me1.w;
    const float n20 = fmaf(me0.z, me0.z, fmaf(me0.y, me0.y, me0.x * me0.x));
    const float n21 = fmaf(me1.z, me1.z, fmaf(me1.y, me1.y, me1.x * me1.x));
    const float thr0 = 4.0f - n20;
    const float thr1 = 4.0f - n21;

    float ax0 = 0.0f, ay0 = 0.0f, az0 = 0.0f;
    float ax1 = 0.0f, ay1 = 0.0f, az1 = 0.0f;

    for (int k0 = 0; k0 < JPS; k0 += GRP) {
        float4 c[GRP];
        #pragma unroll
        for (int g = 0; g < GRP; ++g)
            c[g] = pts[jbase + k0 + g];     // 4-way quarter-wave LDS read
        #pragma unroll
        for (int g = 0; g < GRP; ++g) {
            const float nj = fmaf(c[g].z, c[g].z,
                             fmaf(c[g].y, c[g].y, c[g].x * c[g].x));
            const float sd0 = fmaf(m2z0, c[g].z,
                              fmaf(m2y0, c[g].y, fmaf(m2x0, c[g].x, nj)));
            const float sd1 = fmaf(m2z1, c[g].z,
                              fmaf(m2y1, c[g].y, fmaf(m2x1, c[g].x, nj)));
            if (__any(sd0 < thr0)) {
                const float dist = FAST_SQRT(fmaxf(sd0 + n20, 0.0f));
                const float tgt  = fmaxf(1.0f, ri0 + c[g].w);
                const float p    = fmaxf(tgt - dist, 0.0f);
                const float dx   = fmaf(-0.5f, m2x0, -c[g].x);
                const float dy   = fmaf(-0.5f, m2y0, -c[g].y);
                const float dz   = fmaf(-0.5f, m2z0, -c[g].z);
                ax0 = fmaf(p, clip1(dx), ax0);
                ay0 = fmaf(p, clip1(dy), ay0);
                az0 = fmaf(p, clip1(dz), az0);
            }
            if (__any(sd1 < thr1)) {
                const float dist = FAST_SQRT(fmaxf(sd1 + n21, 0.0f));
                const float tgt  = fmaxf(1.0f, ri1 + c[g].w);
                const float p    = fmaxf(tgt - dist, 0.0f);
                const float dx   = fmaf(-0.5f, m2x1, -c[g].x);
                const float dy   = fmaf(-0.5f, m2y1, -c[g].y);
                const float dz   = fmaf(-0.5f, m2z1, -c[g].z);
                ax1 = fmaf(p, clip1(dx), ax1);
                ay1 = fmaf(p, clip1(dy), ay1);
                az1 = fmaf(p, clip1(dz), az1);
            }
        }
    }

    __syncthreads();                    // all pts reads done before LDS reuse
    {
        const int r0 = (stream * IBL + li) * 3;
        const int r1 = (stream * IBL + 16 + li) * 3;
        red[r0 + 0] = ax0; red[r0 + 1] = ay0; red[r0 + 2] = az0;
        red[r1 + 0] = ax1; red[r1 + 1] = ay1; red[r1 + 2] = az1;
    }
    __syncthreads();

    if (threadIdx.x < IBL * 3) {        // 96 outputs per block
        float acc = 0.0f;
        #pragma unroll
        for (int s = 0; s < STREAMS; ++s)   // ascending s == ascending j
            acc += red[s * (IBL * 3) + threadIdx.x];
        const int o = (b * NN + ibase) * 3 + threadIdx.x;
        out[o] = fmaf(0.1f / (float)NN, acc, coords[o]);
    }
}

extern "C" void kernel_launch(void* const* d_in, const int* in_sizes, int n_in,
                              void* d_out, int out_size, void* d_ws, size_t ws_size,
                              hipStream_t stream) {
    const float* coords = (const float*)d_in[0];
    const float* radii  = (const float*)d_in[1];
    float* out = (float*)d_out;
    (void)d_ws; (void)ws_size;

    ncp_one<<<dim3(NN / IBL, 1, BB), TPB, 0, stream>>>(coords, radii, out);
}